// Round 10
// baseline (282.023 us; speedup 1.0000x reference)
//
#include <hip/hip_runtime.h>
#include <hip/hip_fp16.h>

// Problem constants: B=4, H=W=256, C=64, OC=64, K=3, PAD=1
#define FEAT_N (4*64*256*256)
#define OFFS_N (4*18*256*256)
#define WTF_N  (576*64)            // deform weights, fp16, MFMA-B-fragment order
#define WT2F_N (576*32)            // offset-conv weights, fp16 frags, N padded to 32
#define WT1F_N (4*64*8)            // conv1 weights, fp16 B-frags, K=32 (27 real), N=64

typedef __attribute__((ext_vector_type(8))) _Float16 half8;
typedef __attribute__((ext_vector_type(4))) float float4v;
typedef __attribute__((ext_vector_type(4))) unsigned uint4v;

__device__ __forceinline__ unsigned short f2h(float f) {
    union { __half h; unsigned short u; } c; c.h = __float2half_rn(f); return c.u;
}
__device__ __forceinline__ __half2 u2h2(unsigned u) {
    union { unsigned u; __half2 h; } c; c.u = u; return c.h;
}
__device__ __forceinline__ unsigned h22u(__half2 h) {
    union { __half2 h; unsigned u; } c; c.h = h; return c.u;
}

// ---------------------------------------------------------------------------
// Weight prep (EXACT R9): wtf (deform B-frags), wt2f (offset-conv B-frags,
// oc>=18 zero), wt1f (conv1 B-frags, K padded to 32). All fp16.
// ---------------------------------------------------------------------------
__global__ __launch_bounds__(256) void prep_weights(const float* __restrict__ dw,
                                                    const float* __restrict__ ow,
                                                    const float* __restrict__ cw,
                                                    unsigned short* __restrict__ wtf,
                                                    unsigned short* __restrict__ wt2f,
                                                    unsigned short* __restrict__ wt1f) {
    int idx = blockIdx.x * 256 + threadIdx.x;
    if (idx < WTF_N) {
        int j    = idx & 7;
        int lane = (idx >> 3) & 63;
        int nt   = (idx >> 9) & 3;
        int ks   = idx >> 11;
        int k    = ks * 32 + ((lane >> 4) << 3) + j;
        int tap  = k >> 6;
        int ic   = k & 63;
        int n    = nt * 16 + (lane & 15);
        wtf[idx] = f2h(dw[n * 576 + ic * 9 + tap]);
    }
    int i2 = idx - WTF_N;
    if (i2 >= 0 && i2 < WT2F_N) {
        int j    = i2 & 7;
        int lane = (i2 >> 3) & 63;
        int nt   = (i2 >> 9) & 1;
        int ks   = i2 >> 10;
        int k    = ks * 32 + ((lane >> 4) << 3) + j;
        int tap  = k >> 6;
        int ic   = k & 63;
        int n    = nt * 16 + (lane & 15);
        wt2f[i2] = (n < 18) ? f2h(ow[n * 576 + ic * 9 + tap]) : (unsigned short)0;
    }
    int i3 = idx - WTF_N - WT2F_N;
    if (i3 >= 0 && i3 < WT1F_N) {
        int j    = i3 & 7;
        int lane = (i3 >> 3) & 63;
        int nt   = (i3 >> 9) & 3;
        int n    = nt * 16 + (lane & 15);
        int k    = ((lane >> 4) << 3) + j;
        wt1f[i3] = (k < 27) ? f2h(cw[n * 27 + k]) : (unsigned short)0;
    }
}

// ---------------------------------------------------------------------------
// conv1 (EXACT R9): MFMA im2col GEMM, M=256 px, N=64 oc, K=32, fp16.
// ---------------------------------------------------------------------------
__global__ __launch_bounds__(256) void conv1_kernel(const float* __restrict__ x,
                                                    const unsigned short* __restrict__ wt1f,
                                                    const float* __restrict__ cb,
                                                    unsigned short* __restrict__ featp) {
    __shared__ unsigned short xs[10 * 264];   // rows 0..8 = (ic*3+ti), row 9 = zeros
    const int tid  = threadIdx.x;
    const int lane = tid & 63;
    const int wave = tid >> 6;
    const int lm   = lane & 15;
    const int quad = lane >> 4;

    const int bx = blockIdx.x;
    const int b  = bx >> 8;
    const int h  = bx & 255;

    // ---- stage x halo rows (fp16, zero borders) ----
#pragma unroll
    for (int r = 0; r < 9; r++) {
        const int ic = r / 3, ti = r % 3;                 // static
        const int srow = h - 1 + ti;
        const bool rok = (unsigned)srow < 256u;
        const float* xrow = x + ((b * 3 + ic) << 16) + (srow << 8);
        {
            const int c = tid;                            // c=0..255
            float v = (rok && (unsigned)(c - 1) < 256u) ? xrow[c - 1] : 0.f;
            xs[r * 264 + c] = f2h(v);
        }
        if (tid < 2) {
            const int c = tid + 256;                      // c=256,257
            float v = (rok && (unsigned)(c - 1) < 256u) ? xrow[c - 1] : 0.f;
            xs[r * 264 + c] = f2h(v);
        }
    }
    xs[9 * 264 + tid] = 0;
    if (tid < 8) xs[9 * 264 + 256 + tid] = 0;
    __syncthreads();

    // ---- per-lane A-offsets: k = quad*8+j -> xs row k/3, col-offset k%3 ----
    int off[8];
#pragma unroll
    for (int j = 0; j < 8; j++) {
        const int k = quad * 8 + j;
        const int row = (k < 27) ? (k / 3) : 9;
        const int tj  = (k < 27) ? (k - row * 3) : 0;
        off[j] = row * 264 + tj;
    }

    // ---- B-frags + bias, loaded once ----
    half8 bw[4];
#pragma unroll
    for (int nt = 0; nt < 4; nt++)
        bw[nt] = *(const half8*)(wt1f + nt * 512 + lane * 8);
    float bias[4];
#pragma unroll
    for (int nt = 0; nt < 4; nt++) bias[nt] = cb[nt * 16 + lm];

    unsigned short* fpx = featp + ((((size_t)b << 16) + (h << 8)) << 6);  // +px*64+oc

#pragma unroll
    for (int mt = 0; mt < 4; mt++) {
        const int px = wave * 64 + mt * 16 + lm;          // A-row pixel for this lane
        union { half8 v; unsigned u[4]; } af;
#pragma unroll
        for (int jj = 0; jj < 4; jj++) {
            unsigned lo = xs[off[2 * jj]     + px];
            unsigned hi = xs[off[2 * jj + 1] + px];
            af.u[jj] = lo | (hi << 16);
        }
        float4v d[4];
#pragma unroll
        for (int nt = 0; nt < 4; nt++)
            d[nt] = __builtin_amdgcn_mfma_f32_16x16x32_f16(af.v, bw[nt], (float4v)0.f, 0, 0, 0);

        const int pxs = wave * 64 + mt * 16 + quad * 4;   // D-row pixel base
#pragma unroll
        for (int r = 0; r < 4; r++) {
            unsigned short* sp = fpx + (size_t)(pxs + r) * 64 + lm;
#pragma unroll
            for (int nt = 0; nt < 4; nt++)
                sp[nt * 16] = f2h(d[nt][r] + bias[nt]);
        }
    }
}

// ---------------------------------------------------------------------------
// FUSED conv2 + deform. Phase 1 = R9 (offset conv -> per-wave LDS). Phase 2 =
// deform with DEPTH-2 ping-pong gather pipeline (GA/GB buffers + WA/WB
// bilinear weights, fully static indexing via 9 unrolled STEPs): gathers for
// tap T+2 are issued at step T, giving ~2 taps of latency slack instead of 1.
// ---------------------------------------------------------------------------
__global__ __launch_bounds__(256, 3) void fused_kernel(const unsigned short* __restrict__ featp,
                                                       const unsigned short* __restrict__ wt2f,
                                                       const float* __restrict__ ob,
                                                       const unsigned short* __restrict__ wtf,
                                                       const float* __restrict__ db,
                                                       float* __restrict__ out) {
    __shared__ float offl[4][18 * 33];   // [wave][oc*33 + pxw], 9504 B

    const int tid  = threadIdx.x;
    const int lane = tid & 63;
    const int wave = tid >> 6;
    const int lm   = lane & 15;
    const int quad = lane >> 4;

    const int bx = blockIdx.x;
    const int strip = ((bx & 7) << 8) | (bx >> 3);
    const int wo_base = (strip & 1) << 7;
    const int ho = (strip >> 1) & 255;
    const int b  = strip >> 9;

    const unsigned* fpq = (const unsigned*)featp + ((size_t)b << 21) + quad * 4;
    const int colb = wo_base + wave * 32 + lm;
    float* offw = &offl[wave][0];

    // ================= PHASE 1: offset conv (EXACT R9) =================
    {
        float4v acc[2][2];
#pragma unroll
        for (int mt = 0; mt < 2; mt++)
#pragma unroll
            for (int nt = 0; nt < 2; nt++) acc[mt][nt] = (float4v)0.f;

        uint4v A[2][2];

#define C2LOAD(KY, KX, DST)                                                      \
    {                                                                            \
        const int row = ho - 1 + (KY);                                           \
        const bool rok = (unsigned)row < 256u;                                   \
        _Pragma("unroll")                                                        \
        for (int mt = 0; mt < 2; mt++) {                                         \
            const int col = colb + mt * 16 + (KX) - 1;                           \
            DST[mt][0] = (uint4v)0;                                              \
            DST[mt][1] = (uint4v)0;                                              \
            if (rok && (unsigned)col < 256u) {                                   \
                const unsigned* p = fpq + (((row << 8) + col) << 5);             \
                DST[mt][0] = *(const uint4v*)p;                                  \
                DST[mt][1] = *(const uint4v*)(p + 16);                           \
            }                                                                    \
        }                                                                        \
    }

        C2LOAD(0, 0, A);

#pragma unroll
        for (int tap = 0; tap < 9; tap++) {
            half8 bfr[2][2];
            const unsigned short* wp = wt2f + (size_t)(tap * 2) * 1024 + lane * 8;
#pragma unroll
            for (int st = 0; st < 2; st++) {
                bfr[st][0] = *(const half8*)(wp + st * 1024);
                bfr[st][1] = *(const half8*)(wp + st * 1024 + 512);
            }
            uint4v N[2][2];
            if (tap < 8) {
                const int tn  = tap + 1;
                const int tky = tn / 3;
                const int tkx = tn - 3 * tky;
                C2LOAD(tky, tkx, N);
            }
#pragma unroll
            for (int mt = 0; mt < 2; mt++) {
                union { half8 v; uint4v u; } f0, f1;
                f0.u = A[mt][0]; f1.u = A[mt][1];
                acc[mt][0] = __builtin_amdgcn_mfma_f32_16x16x32_f16(f0.v, bfr[0][0], acc[mt][0], 0, 0, 0);
                acc[mt][1] = __builtin_amdgcn_mfma_f32_16x16x32_f16(f0.v, bfr[0][1], acc[mt][1], 0, 0, 0);
                acc[mt][0] = __builtin_amdgcn_mfma_f32_16x16x32_f16(f1.v, bfr[1][0], acc[mt][0], 0, 0, 0);
                acc[mt][1] = __builtin_amdgcn_mfma_f32_16x16x32_f16(f1.v, bfr[1][1], acc[mt][1], 0, 0, 0);
            }
            if (tap < 8) {
#pragma unroll
                for (int mt = 0; mt < 2; mt++) {
                    A[mt][0] = N[mt][0];
                    A[mt][1] = N[mt][1];
                }
            }
        }
#undef C2LOAD

        // Store offsets to per-wave LDS. pxw = mt*16+quad*4+r.
#pragma unroll
        for (int nt = 0; nt < 2; nt++) {
            int oc = nt * 16 + lm;
            if (oc < 18) {
                float bv = ob[oc];
#pragma unroll
                for (int mt = 0; mt < 2; mt++) {
#pragma unroll
                    for (int r = 0; r < 4; r++)
                        offw[oc * 33 + mt * 16 + quad * 4 + r] = acc[mt][nt][r] + bv;
                }
            }
        }
    }
    // Intra-wave producer/consumer: each wave reads only its own offl[wave].

    // ================= PHASE 2: deform conv (depth-2 pipeline) ================
    const int wo0 = wo_base + wave * 32 + lm;       // mt=0 pixel; mt=1 is +16

    float4v acc[2][4];
#pragma unroll
    for (int mt = 0; mt < 2; mt++)
#pragma unroll
        for (int nt = 0; nt < 4; nt++) acc[mt][nt] = (float4v)0.f;

    unsigned e00[2], e01[2], e10[2], e11[2];
    __half2 WA[2][4], WB[2][4];          // bilinear weights, [mt][corner], 2-deep
    uint4v GA[2][4][2], GB[2][4][2];     // gather buffers, [mt][corner][step]

    union AFU { half8 v; unsigned u[4]; };

#define COORDS(MT, KY, KX, OY, OX, W)                                            \
    {                                                                            \
        float sy = (float)(ho - 1 + (KY)) + (OY);                                \
        float sx = (float)(wo0 + (MT) * 16 - 1 + (KX)) + (OX);                   \
        float y0f = floorf(sy), x0f = floorf(sx);                                \
        float dy = sy - y0f, dx = sx - x0f;                                      \
        int y0 = (int)y0f, x0 = (int)x0f;                                        \
        float wy0 = ((unsigned)y0 < 256u) ? (1.f - dy) : 0.f;                    \
        float wy1 = ((unsigned)(y0 + 1) < 256u) ? dy : 0.f;                      \
        float wx0 = ((unsigned)x0 < 256u) ? (1.f - dx) : 0.f;                    \
        float wx1 = ((unsigned)(x0 + 1) < 256u) ? dx : 0.f;                      \
        int yb0 = y0 < 0 ? 0 : (y0 > 255 ? 255 : y0);                            \
        int yb1 = (y0 + 1) < 0 ? 0 : ((y0 + 1) > 255 ? 255 : (y0 + 1));          \
        int xb0 = x0 < 0 ? 0 : (x0 > 255 ? 255 : x0);                            \
        int xb1 = (x0 + 1) < 0 ? 0 : ((x0 + 1) > 255 ? 255 : (x0 + 1));          \
        W[MT][0] = __float2half2_rn(wy0 * wx0);                                  \
        W[MT][1] = __float2half2_rn(wy0 * wx1);                                  \
        W[MT][2] = __float2half2_rn(wy1 * wx0);                                  \
        W[MT][3] = __float2half2_rn(wy1 * wx1);                                  \
        e00[MT] = ((yb0 << 8) + xb0) << 5; e01[MT] = ((yb0 << 8) + xb1) << 5;    \
        e10[MT] = ((yb1 << 8) + xb0) << 5; e11[MT] = ((yb1 << 8) + xb1) << 5;    \
    }

#define ISSUE(MT, G)                                                             \
    {                                                                            \
        G[MT][0][0] = *(const uint4v*)(fpq + e00[MT]);                           \
        G[MT][0][1] = *(const uint4v*)(fpq + e00[MT] + 16);                      \
        G[MT][1][0] = *(const uint4v*)(fpq + e01[MT]);                           \
        G[MT][1][1] = *(const uint4v*)(fpq + e01[MT] + 16);                      \
        G[MT][2][0] = *(const uint4v*)(fpq + e10[MT]);                           \
        G[MT][2][1] = *(const uint4v*)(fpq + e10[MT] + 16);                      \
        G[MT][3][0] = *(const uint4v*)(fpq + e11[MT]);                           \
        G[MT][3][1] = *(const uint4v*)(fpq + e11[MT] + 16);                      \
    }

#define COMBINE(MT, AF, G, W)                                                    \
    _Pragma("unroll")                                                            \
    for (int st = 0; st < 2; st++) {                                             \
        _Pragma("unroll")                                                        \
        for (int j = 0; j < 4; j++) {                                            \
            __half2 s = __hmul2(W[MT][0], u2h2(G[MT][0][st][j]));                \
            s = __hfma2(W[MT][1], u2h2(G[MT][1][st][j]), s);                     \
            s = __hfma2(W[MT][2], u2h2(G[MT][2][st][j]), s);                     \
            s = __hfma2(W[MT][3], u2h2(G[MT][3][st][j]), s);                     \
            AF[st].u[j] = h22u(s);                                               \
        }                                                                        \
    }

#define MFMA_MT(MT, AF)                                                          \
    _Pragma("unroll")                                                            \
    for (int nt = 0; nt < 4; nt++)                                               \
        acc[MT][nt] = __builtin_amdgcn_mfma_f32_16x16x32_f16(                    \
            AF[0].v, bfr[0][nt], acc[MT][nt], 0, 0, 0);                          \
    _Pragma("unroll")                                                            \
    for (int nt = 0; nt < 4; nt++)                                               \
        acc[MT][nt] = __builtin_amdgcn_mfma_f32_16x16x32_f16(                    \
            AF[1].v, bfr[1][nt], acc[MT][nt], 0, 0, 0);

// One pipeline step: consume buffer G/W (tap T), refill with tap T+2.
#define STEP(T, G, W)                                                            \
    {                                                                            \
        float ny0 = 0.f, nx0 = 0.f, ny1 = 0.f, nx1 = 0.f;                        \
        if ((T) + 2 <= 8) {                                                      \
            const float* p = offw + (2 * (T) + 4) * 33;                          \
            ny0 = p[lm];      ny1 = p[lm + 16];                                  \
            nx0 = p[33 + lm]; nx1 = p[33 + lm + 16];                             \
        }                                                                        \
        half8 bfr[2][4];                                                         \
        {                                                                        \
            const unsigned short* wp = wtf + (size_t)(T) * 4096 + lane * 8;      \
            _Pragma("unroll")                                                    \
            for (int nt = 0; nt < 4; nt++) {                                     \
                bfr[0][nt] = *(const half8*)(wp + (nt << 9));                    \
                bfr[1][nt] = *(const half8*)(wp + 2048 + (nt << 9));             \
            }                                                                    \
        }                                                                        \
        AFU af[2];                                                               \
        COMBINE(0, af, G, W);                                                    \
        MFMA_MT(0, af);                                                          \
        if ((T) + 2 <= 8) {                                                      \
            COORDS(0, ((T) + 2) / 3, ((T) + 2) % 3, ny0, nx0, W);                \
            ISSUE(0, G);                                                         \
        }                                                                        \
        COMBINE(1, af, G, W);                                                    \
        MFMA_MT(1, af);                                                          \
        if ((T) + 2 <= 8) {                                                      \
            COORDS(1, ((T) + 2) / 3, ((T) + 2) % 3, ny1, nx1, W);                \
            ISSUE(1, G);                                                         \
        }                                                                        \
    }

    // Prologue: tap 0 -> GA/WA, tap 1 -> GB/WB
    {
        float a0 = offw[0 * 33 + lm],      a1 = offw[1 * 33 + lm];
        float a2 = offw[0 * 33 + lm + 16], a3 = offw[1 * 33 + lm + 16];
        COORDS(0, 0, 0, a0, a1, WA); ISSUE(0, GA);
        COORDS(1, 0, 0, a2, a3, WA); ISSUE(1, GA);
        float b0 = offw[2 * 33 + lm],      b1 = offw[3 * 33 + lm];
        float b2 = offw[2 * 33 + lm + 16], b3 = offw[3 * 33 + lm + 16];
        COORDS(0, 0, 1, b0, b1, WB); ISSUE(0, GB);
        COORDS(1, 0, 1, b2, b3, WB); ISSUE(1, GB);
    }

    STEP(0, GA, WA); STEP(1, GB, WB);
    STEP(2, GA, WA); STEP(3, GB, WB);
    STEP(4, GA, WA); STEP(5, GB, WB);
    STEP(6, GA, WA); STEP(7, GB, WB);
    STEP(8, GA, WA);

#pragma unroll
    for (int nt = 0; nt < 4; nt++) {
        int oc = nt * 16 + lm;
        float bv = db[oc];
        float* op = out + (((size_t)(b * 64 + oc)) << 16) + (ho << 8)
                  + wo_base + wave * 32 + quad * 4;
#pragma unroll
        for (int mt = 0; mt < 2; mt++) {
            float4 v = {acc[mt][nt][0] + bv, acc[mt][nt][1] + bv,
                        acc[mt][nt][2] + bv, acc[mt][nt][3] + bv};
            *(float4*)(op + mt * 16) = v;
        }
    }
#undef COORDS
#undef ISSUE
#undef COMBINE
#undef MFMA_MT
#undef STEP
}

// ---------------------------------------------------------------------------
extern "C" void kernel_launch(void* const* d_in, const int* in_sizes, int n_in,
                              void* d_out, int out_size, void* d_ws, size_t ws_size,
                              hipStream_t stream) {
    const float* x  = (const float*)d_in[0];
    const float* cw = (const float*)d_in[1];
    const float* cb = (const float*)d_in[2];
    const float* ow = (const float*)d_in[3];
    const float* ob = (const float*)d_in[4];
    const float* dw = (const float*)d_in[5];
    const float* db = (const float*)d_in[6];
    float* out = (float*)d_out;

    unsigned short* featp = (unsigned short*)d_ws;       // 33.5 MB fp16 NHWC
    float* offsb = (float*)(featp + FEAT_N);             // dead region — reuse
    unsigned short* wt1f = (unsigned short*)offsb;       // 4 KB conv1 B-frags
    unsigned short* wtf  = (unsigned short*)(offsb + OFFS_N);  // 72 KB
    unsigned short* wt2f = wtf + WTF_N;                  // 36 KB

    prep_weights<<<224, 256, 0, stream>>>(dw, ow, cw, wtf, wt2f, wt1f);
    conv1_kernel<<<1024, 256, 0, stream>>>(x, wt1f, cb, featp);
    fused_kernel<<<2048, 256, 0, stream>>>(featp, wt2f, ob, wtf, db, out);
}

// Round 12
// 213.754 us; speedup vs baseline: 1.3194x; 1.3194x over previous
//
#include <hip/hip_runtime.h>
#include <hip/hip_fp16.h>

// Problem constants: B=4, H=W=256, C=64, OC=64, K=3, PAD=1
#define FEAT_N (4*64*256*256)
#define OFFS_N (4*18*256*256)
#define WTF_N  (576*64)            // deform weights, fp16, MFMA-B-fragment order
#define WT2F_N (576*32)            // offset-conv weights, fp16 frags, N padded to 32
#define WT1F_N (4*64*8)            // conv1 weights, fp16 B-frags, K=32 (27 real), N=64

typedef __attribute__((ext_vector_type(8))) _Float16 half8;
typedef __attribute__((ext_vector_type(4))) float float4v;
typedef __attribute__((ext_vector_type(4))) unsigned uint4v;

__device__ __forceinline__ unsigned short f2h(float f) {
    union { __half h; unsigned short u; } c; c.h = __float2half_rn(f); return c.u;
}
__device__ __forceinline__ __half2 u2h2(unsigned u) {
    union { unsigned u; __half2 h; } c; c.u = u; return c.h;
}
__device__ __forceinline__ unsigned h22u(__half2 h) {
    union { __half2 h; unsigned u; } c; c.h = h; return c.u;
}

// ---------------------------------------------------------------------------
// Weight prep (EXACT R9): wtf (deform B-frags), wt2f (offset-conv B-frags,
// oc>=18 zero), wt1f (conv1 B-frags, K padded to 32). All fp16.
// ---------------------------------------------------------------------------
__global__ __launch_bounds__(256) void prep_weights(const float* __restrict__ dw,
                                                    const float* __restrict__ ow,
                                                    const float* __restrict__ cw,
                                                    unsigned short* __restrict__ wtf,
                                                    unsigned short* __restrict__ wt2f,
                                                    unsigned short* __restrict__ wt1f) {
    int idx = blockIdx.x * 256 + threadIdx.x;
    if (idx < WTF_N) {
        int j    = idx & 7;
        int lane = (idx >> 3) & 63;
        int nt   = (idx >> 9) & 3;
        int ks   = idx >> 11;
        int k    = ks * 32 + ((lane >> 4) << 3) + j;
        int tap  = k >> 6;
        int ic   = k & 63;
        int n    = nt * 16 + (lane & 15);
        wtf[idx] = f2h(dw[n * 576 + ic * 9 + tap]);
    }
    int i2 = idx - WTF_N;
    if (i2 >= 0 && i2 < WT2F_N) {
        int j    = i2 & 7;
        int lane = (i2 >> 3) & 63;
        int nt   = (i2 >> 9) & 1;
        int ks   = i2 >> 10;
        int k    = ks * 32 + ((lane >> 4) << 3) + j;
        int tap  = k >> 6;
        int ic   = k & 63;
        int n    = nt * 16 + (lane & 15);
        wt2f[i2] = (n < 18) ? f2h(ow[n * 576 + ic * 9 + tap]) : (unsigned short)0;
    }
    int i3 = idx - WTF_N - WT2F_N;
    if (i3 >= 0 && i3 < WT1F_N) {
        int j    = i3 & 7;
        int lane = (i3 >> 3) & 63;
        int nt   = (i3 >> 9) & 3;
        int n    = nt * 16 + (lane & 15);
        int k    = ((lane >> 4) << 3) + j;
        wt1f[i3] = (k < 27) ? f2h(cw[n * 27 + k]) : (unsigned short)0;
    }
}

// ---------------------------------------------------------------------------
// conv1 (EXACT R9): MFMA im2col GEMM, M=256 px, N=64 oc, K=32, fp16.
// ---------------------------------------------------------------------------
__global__ __launch_bounds__(256) void conv1_kernel(const float* __restrict__ x,
                                                    const unsigned short* __restrict__ wt1f,
                                                    const float* __restrict__ cb,
                                                    unsigned short* __restrict__ featp) {
    __shared__ unsigned short xs[10 * 264];   // rows 0..8 = (ic*3+ti), row 9 = zeros
    const int tid  = threadIdx.x;
    const int lane = tid & 63;
    const int wave = tid >> 6;
    const int lm   = lane & 15;
    const int quad = lane >> 4;

    const int bx = blockIdx.x;
    const int b  = bx >> 8;
    const int h  = bx & 255;

    // ---- stage x halo rows (fp16, zero borders) ----
#pragma unroll
    for (int r = 0; r < 9; r++) {
        const int ic = r / 3, ti = r % 3;                 // static
        const int srow = h - 1 + ti;
        const bool rok = (unsigned)srow < 256u;
        const float* xrow = x + ((b * 3 + ic) << 16) + (srow << 8);
        {
            const int c = tid;                            // c=0..255
            float v = (rok && (unsigned)(c - 1) < 256u) ? xrow[c - 1] : 0.f;
            xs[r * 264 + c] = f2h(v);
        }
        if (tid < 2) {
            const int c = tid + 256;                      // c=256,257
            float v = (rok && (unsigned)(c - 1) < 256u) ? xrow[c - 1] : 0.f;
            xs[r * 264 + c] = f2h(v);
        }
    }
    xs[9 * 264 + tid] = 0;
    if (tid < 8) xs[9 * 264 + 256 + tid] = 0;
    __syncthreads();

    // ---- per-lane A-offsets: k = quad*8+j -> xs row k/3, col-offset k%3 ----
    int off[8];
#pragma unroll
    for (int j = 0; j < 8; j++) {
        const int k = quad * 8 + j;
        const int row = (k < 27) ? (k / 3) : 9;
        const int tj  = (k < 27) ? (k - row * 3) : 0;
        off[j] = row * 264 + tj;
    }

    // ---- B-frags + bias, loaded once ----
    half8 bw[4];
#pragma unroll
    for (int nt = 0; nt < 4; nt++)
        bw[nt] = *(const half8*)(wt1f + nt * 512 + lane * 8);
    float bias[4];
#pragma unroll
    for (int nt = 0; nt < 4; nt++) bias[nt] = cb[nt * 16 + lm];

    unsigned short* fpx = featp + ((((size_t)b << 16) + (h << 8)) << 6);  // +px*64+oc

#pragma unroll
    for (int mt = 0; mt < 4; mt++) {
        const int px = wave * 64 + mt * 16 + lm;          // A-row pixel for this lane
        union { half8 v; unsigned u[4]; } af;
#pragma unroll
        for (int jj = 0; jj < 4; jj++) {
            unsigned lo = xs[off[2 * jj]     + px];
            unsigned hi = xs[off[2 * jj + 1] + px];
            af.u[jj] = lo | (hi << 16);
        }
        float4v d[4];
#pragma unroll
        for (int nt = 0; nt < 4; nt++)
            d[nt] = __builtin_amdgcn_mfma_f32_16x16x32_f16(af.v, bw[nt], (float4v)0.f, 0, 0, 0);

        const int pxs = wave * 64 + mt * 16 + quad * 4;   // D-row pixel base
#pragma unroll
        for (int r = 0; r < 4; r++) {
            unsigned short* sp = fpx + (size_t)(pxs + r) * 64 + lm;
#pragma unroll
            for (int nt = 0; nt < 4; nt++)
                sp[nt * 16] = f2h(d[nt][r] + bias[nt]);
        }
    }
}

// ---------------------------------------------------------------------------
// FUSED conv2 + deform. Phase 1 = EXACT R9 (offset conv -> per-wave LDS).
// Phase 2 = deform gathering from an LDS ring window instead of global:
//   ring = 4 rows x 132 px x 128 B (66 KB), rows (ho-2+ky .. ho+ky+1),
//   advanced 1 row per ky (2 barriers per advance). XOR swizzle
//   (byte ^ (xslot&7)<<4) kills the 128B-stride bank conflict.
//   Per (tap,mt): wave-uniform __all(in-window) -> LDS path (bit-identical
//   data) else the original global-gather path (correctness fallback).
// This converts ~144 divergent global gathers/wave (TA-bound) into LDS reads.
// ---------------------------------------------------------------------------
__global__ __launch_bounds__(256, 2) void fused_kernel(const unsigned short* __restrict__ featp,
                                                       const unsigned short* __restrict__ wt2f,
                                                       const float* __restrict__ ob,
                                                       const unsigned short* __restrict__ wtf,
                                                       const float* __restrict__ db,
                                                       float* __restrict__ out) {
    __shared__ __align__(16) unsigned char ring[4 * 132 * 128];   // 67584 B
    __shared__ float offl[4][18 * 33];                            // 9504 B

    const int tid  = threadIdx.x;
    const int lane = tid & 63;
    const int wave = tid >> 6;
    const int lm   = lane & 15;
    const int quad = lane >> 4;

    const int bx = blockIdx.x;
    const int strip = ((bx & 7) << 8) | (bx >> 3);
    const int wo_base = (strip & 1) << 7;
    const int ho = (strip >> 1) & 255;
    const int b  = strip >> 9;

    const unsigned* fpq = (const unsigned*)featp + ((size_t)b << 21) + quad * 4;
    const int colb = wo_base + wave * 32 + lm;
    float* offw = &offl[wave][0];

    const char* gbase = (const char*)featp + (((size_t)b << 16) << 7);  // batch byte base

// Stage feature row R (if valid) into ring slot R&3, swizzled. Covers cols
// [wo_base-2, wo_base+129]; invalid cols skipped (stale LDS never read).
#define STAGE_ROW(R)                                                             \
    {                                                                            \
        const int rr = (R);                                                      \
        if ((unsigned)rr < 256u) {                                               \
            const char* gsrc = gbase + ((size_t)(rr << 8) << 7);                 \
            const unsigned base = (unsigned)((rr & 3) * 16896);                  \
            for (int c = tid; c < 1056; c += 256) {                              \
                const int xsl = c >> 3;                                          \
                const int col = wo_base - 2 + xsl;                               \
                if ((unsigned)col < 256u) {                                      \
                    uint4v v = *(const uint4v*)(gsrc + (((size_t)col) << 7)      \
                                                + ((c & 7) << 4));               \
                    const unsigned by = base + (unsigned)(c << 4);               \
                    *(uint4v*)(ring + (by ^ ((unsigned)((xsl & 7) << 4)))) = v;  \
                }                                                                \
            }                                                                    \
        }                                                                        \
    }

    // ---- issue initial window staging (rows ho-2..ho+1); completes under
    //      phase-1 compute; barrier after phase 1 publishes it. ----
    STAGE_ROW(ho - 2);
    STAGE_ROW(ho - 1);
    STAGE_ROW(ho);
    STAGE_ROW(ho + 1);

    // ================= PHASE 1: offset conv (EXACT R9) =================
    {
        float4v acc[2][2];
#pragma unroll
        for (int mt = 0; mt < 2; mt++)
#pragma unroll
            for (int nt = 0; nt < 2; nt++) acc[mt][nt] = (float4v)0.f;

        uint4v A[2][2];

#define C2LOAD(KY, KX, DST)                                                      \
    {                                                                            \
        const int row = ho - 1 + (KY);                                           \
        const bool rok = (unsigned)row < 256u;                                   \
        _Pragma("unroll")                                                        \
        for (int mt = 0; mt < 2; mt++) {                                         \
            const int col = colb + mt * 16 + (KX) - 1;                           \
            DST[mt][0] = (uint4v)0;                                              \
            DST[mt][1] = (uint4v)0;                                              \
            if (rok && (unsigned)col < 256u) {                                   \
                const unsigned* p = fpq + (((row << 8) + col) << 5);             \
                DST[mt][0] = *(const uint4v*)p;                                  \
                DST[mt][1] = *(const uint4v*)(p + 16);                           \
            }                                                                    \
        }                                                                        \
    }

        C2LOAD(0, 0, A);

#pragma unroll
        for (int tap = 0; tap < 9; tap++) {
            half8 bfr[2][2];
            const unsigned short* wp = wt2f + (size_t)(tap * 2) * 1024 + lane * 8;
#pragma unroll
            for (int st = 0; st < 2; st++) {
                bfr[st][0] = *(const half8*)(wp + st * 1024);
                bfr[st][1] = *(const half8*)(wp + st * 1024 + 512);
            }
            uint4v N[2][2];
            if (tap < 8) {
                const int tn  = tap + 1;
                const int tky = tn / 3;
                const int tkx = tn - 3 * tky;
                C2LOAD(tky, tkx, N);
            }
#pragma unroll
            for (int mt = 0; mt < 2; mt++) {
                union { half8 v; uint4v u; } f0, f1;
                f0.u = A[mt][0]; f1.u = A[mt][1];
                acc[mt][0] = __builtin_amdgcn_mfma_f32_16x16x32_f16(f0.v, bfr[0][0], acc[mt][0], 0, 0, 0);
                acc[mt][1] = __builtin_amdgcn_mfma_f32_16x16x32_f16(f0.v, bfr[0][1], acc[mt][1], 0, 0, 0);
                acc[mt][0] = __builtin_amdgcn_mfma_f32_16x16x32_f16(f1.v, bfr[1][0], acc[mt][0], 0, 0, 0);
                acc[mt][1] = __builtin_amdgcn_mfma_f32_16x16x32_f16(f1.v, bfr[1][1], acc[mt][1], 0, 0, 0);
            }
            if (tap < 8) {
#pragma unroll
                for (int mt = 0; mt < 2; mt++) {
                    A[mt][0] = N[mt][0];
                    A[mt][1] = N[mt][1];
                }
            }
        }
#undef C2LOAD

        // Store offsets to per-wave LDS. pxw = mt*16+quad*4+r.
#pragma unroll
        for (int nt = 0; nt < 2; nt++) {
            int oc = nt * 16 + lm;
            if (oc < 18) {
                float bv = ob[oc];
#pragma unroll
                for (int mt = 0; mt < 2; mt++) {
#pragma unroll
                    for (int r = 0; r < 4; r++)
                        offw[oc * 33 + mt * 16 + quad * 4 + r] = acc[mt][nt][r] + bv;
                }
            }
        }
    }

    __syncthreads();   // ring window (ho-2..ho+1) published

    // ================= PHASE 2: deform conv (LDS-window gathers) ============
    const int wo0 = wo_base + wave * 32 + lm;       // mt=0 pixel; mt=1 is +16

    float4v acc[2][4];
#pragma unroll
    for (int mt = 0; mt < 2; mt++)
#pragma unroll
        for (int nt = 0; nt < 4; nt++) acc[mt][nt] = (float4v)0.f;

    union AFU { half8 v; unsigned u[4]; };

// One (tap, mt): coords -> window vote -> LDS or global gather -> packed-fp16
// combine -> 8 MFMA. Gathered bits identical on both paths.
#define DOTAP_MT(MT, KY, KX, OY, OX)                                             \
    {                                                                            \
        float sy = (float)(ho - 1 + (KY)) + (OY);                                \
        float sx = (float)(wo0 + (MT) * 16 - 1 + (KX)) + (OX);                   \
        float y0f = floorf(sy), x0f = floorf(sx);                                \
        float dy = sy - y0f, dx = sx - x0f;                                      \
        int y0 = (int)y0f, x0 = (int)x0f;                                        \
        float wy0 = ((unsigned)y0 < 256u) ? (1.f - dy) : 0.f;                    \
        float wy1 = ((unsigned)(y0 + 1) < 256u) ? dy : 0.f;                      \
        float wx0 = ((unsigned)x0 < 256u) ? (1.f - dx) : 0.f;                    \
        float wx1 = ((unsigned)(x0 + 1) < 256u) ? dx : 0.f;                      \
        int yb0 = y0 < 0 ? 0 : (y0 > 255 ? 255 : y0);                            \
        int yb1 = (y0 + 1) < 0 ? 0 : ((y0 + 1) > 255 ? 255 : (y0 + 1));          \
        int xb0 = x0 < 0 ? 0 : (x0 > 255 ? 255 : x0);                            \
        int xb1 = (x0 + 1) < 0 ? 0 : ((x0 + 1) > 255 ? 255 : (x0 + 1));          \
        __half2 W0 = __float2half2_rn(wy0 * wx0);                                \
        __half2 W1 = __float2half2_rn(wy0 * wx1);                                \
        __half2 W2 = __float2half2_rn(wy1 * wx0);                                \
        __half2 W3 = __float2half2_rn(wy1 * wx1);                                \
        uint4v Gg[4][2];                                                         \
        bool inw = (yb0 >= ho - 2 + (KY)) && (yb1 <= ho + (KY) + 1) &&           \
                   (xb0 >= wo_base - 2) && (xb1 <= wo_base + 129);               \
        if (__all(inw)) {                                                        \
            const int xs0 = xb0 - wo_base + 2, xs1 = xb1 - wo_base + 2;          \
            const unsigned m0 = (unsigned)((xs0 & 7) << 4);                      \
            const unsigned m1 = (unsigned)((xs1 & 7) << 4);                      \
            const unsigned r0b = (unsigned)((yb0 & 3) * 16896 + quad * 16);      \
            const unsigned r1b = (unsigned)((yb1 & 3) * 16896 + quad * 16);      \
            const unsigned a00 = r0b + (unsigned)(xs0 << 7);                     \
            const unsigned a01 = r0b + (unsigned)(xs1 << 7);                     \
            const unsigned a10 = r1b + (unsigned)(xs0 << 7);                     \
            const unsigned a11 = r1b + (unsigned)(xs1 << 7);                     \
            Gg[0][0] = *(const uint4v*)(ring + (a00 ^ m0));                      \
            Gg[0][1] = *(const uint4v*)(ring + ((a00 + 64) ^ m0));               \
            Gg[1][0] = *(const uint4v*)(ring + (a01 ^ m1));                      \
            Gg[1][1] = *(const uint4v*)(ring + ((a01 + 64) ^ m1));               \
            Gg[2][0] = *(const uint4v*)(ring + (a10 ^ m0));                      \
            Gg[2][1] = *(const uint4v*)(ring + ((a10 + 64) ^ m0));               \
            Gg[3][0] = *(const uint4v*)(ring + (a11 ^ m1));                      \
            Gg[3][1] = *(const uint4v*)(ring + ((a11 + 64) ^ m1));               \
        } else {                                                                 \
            const unsigned e00 = ((yb0 << 8) + xb0) << 5;                        \
            const unsigned e01 = ((yb0 << 8) + xb1) << 5;                        \
            const unsigned e10 = ((yb1 << 8) + xb0) << 5;                        \
            const unsigned e11 = ((yb1 << 8) + xb1) << 5;                        \
            Gg[0][0] = *(const uint4v*)(fpq + e00);                              \
            Gg[0][1] = *(const uint4v*)(fpq + e00 + 16);                         \
            Gg[1][0] = *(const uint4v*)(fpq + e01);                              \
            Gg[1][1] = *(const uint4v*)(fpq + e01 + 16);                         \
            Gg[2][0] = *(const uint4v*)(fpq + e10);                              \
            Gg[2][1] = *(const uint4v*)(fpq + e10 + 16);                         \
            Gg[3][0] = *(const uint4v*)(fpq + e11);                              \
            Gg[3][1] = *(const uint4v*)(fpq + e11 + 16);                         \
        }                                                                        \
        AFU af[2];                                                               \
        _Pragma("unroll")                                                        \
        for (int st = 0; st < 2; st++) {                                         \
            _Pragma("unroll")                                                    \
            for (int j = 0; j < 4; j++) {                                        \
                __half2 s = __hmul2(W0, u2h2(Gg[0][st][j]));                     \
                s = __hfma2(W1, u2h2(Gg[1][st][j]), s);                          \
                s = __hfma2(W2, u2h2(Gg[2][st][j]), s);                          \
                s = __hfma2(W3, u2h2(Gg[3][st][j]), s);                          \
                af[st].u[j] = h22u(s);                                           \
            }                                                                    \
        }                                                                        \
        _Pragma("unroll")                                                        \
        for (int nt = 0; nt < 4; nt++)                                           \
            acc[MT][nt] = __builtin_amdgcn_mfma_f32_16x16x32_f16(                \
                af[0].v, bfr[0][nt], acc[MT][nt], 0, 0, 0);                      \
        _Pragma("unroll")                                                        \
        for (int nt = 0; nt < 4; nt++)                                           \
            acc[MT][nt] = __builtin_amdgcn_mfma_f32_16x16x32_f16(                \
                af[1].v, bfr[1][nt], acc[MT][nt], 0, 0, 0);                      \
    }

#pragma unroll
    for (int tap = 0; tap < 9; ++tap) {
        const int ky = tap / 3;
        const int kx = tap - 3 * ky;
        if (tap == 3) { __syncthreads(); STAGE_ROW(ho + 2); __syncthreads(); }
        if (tap == 6) { __syncthreads(); STAGE_ROW(ho + 3); __syncthreads(); }

        float oy0 = offw[(2 * tap) * 33 + lm];
        float ox0 = offw[(2 * tap + 1) * 33 + lm];
        float oy1 = offw[(2 * tap) * 33 + lm + 16];
        float ox1 = offw[(2 * tap + 1) * 33 + lm + 16];

        half8 bfr[2][4];                                // B-frags, both steps
        {
            const unsigned short* wp = wtf + (size_t)tap * 4096 + lane * 8;
#pragma unroll
            for (int nt = 0; nt < 4; nt++) {
                bfr[0][nt] = *(const half8*)(wp + (nt << 9));
                bfr[1][nt] = *(const half8*)(wp + 2048 + (nt << 9));
            }
        }

        DOTAP_MT(0, ky, kx, oy0, ox0);
        DOTAP_MT(1, ky, kx, oy1, ox1);
    }

#pragma unroll
    for (int nt = 0; nt < 4; nt++) {
        int oc = nt * 16 + lm;
        float bv = db[oc];
        float* op = out + (((size_t)(b * 64 + oc)) << 16) + (ho << 8)
                  + wo_base + wave * 32 + quad * 4;
#pragma unroll
        for (int mt = 0; mt < 2; mt++) {
            float4 v = {acc[mt][nt][0] + bv, acc[mt][nt][1] + bv,
                        acc[mt][nt][2] + bv, acc[mt][nt][3] + bv};
            *(float4*)(op + mt * 16) = v;
        }
    }
#undef DOTAP_MT
#undef STAGE_ROW
}

// ---------------------------------------------------------------------------
extern "C" void kernel_launch(void* const* d_in, const int* in_sizes, int n_in,
                              void* d_out, int out_size, void* d_ws, size_t ws_size,
                              hipStream_t stream) {
    const float* x  = (const float*)d_in[0];
    const float* cw = (const float*)d_in[1];
    const float* cb = (const float*)d_in[2];
    const float* ow = (const float*)d_in[3];
    const float* ob = (const float*)d_in[4];
    const float* dw = (const float*)d_in[5];
    const float* db = (const float*)d_in[6];
    float* out = (float*)d_out;

    unsigned short* featp = (unsigned short*)d_ws;       // 33.5 MB fp16 NHWC
    float* offsb = (float*)(featp + FEAT_N);             // dead region — reuse
    unsigned short* wt1f = (unsigned short*)offsb;       // 4 KB conv1 B-frags
    unsigned short* wtf  = (unsigned short*)(offsb + OFFS_N);  // 72 KB
    unsigned short* wt2f = wtf + WTF_N;                  // 36 KB

    prep_weights<<<224, 256, 0, stream>>>(dw, ow, cw, wtf, wt2f, wt1f);
    conv1_kernel<<<1024, 256, 0, stream>>>(x, wt1f, cb, featp);
    fused_kernel<<<2048, 256, 0, stream>>>(featp, wt2f, ob, wtf, db, out);
}

// Round 13
// 213.165 us; speedup vs baseline: 1.3230x; 1.0028x over previous
//
#include <hip/hip_runtime.h>
#include <hip/hip_fp16.h>

// Problem constants: B=4, H=W=256, C=64, OC=64, K=3, PAD=1
#define FEAT_N (4*64*256*256)
#define OFFS_N (4*18*256*256)
#define WTF_N  (576*64)            // deform weights, fp16, MFMA-B-fragment order
#define WT2F_N (576*32)            // offset-conv weights, fp16 frags, N padded to 32
#define WT1F_N (4*64*8)            // conv1 weights, fp16 B-frags, K=32 (27 real), N=64

typedef __attribute__((ext_vector_type(8))) _Float16 half8;
typedef __attribute__((ext_vector_type(4))) float float4v;
typedef __attribute__((ext_vector_type(4))) unsigned uint4v;

__device__ __forceinline__ unsigned short f2h(float f) {
    union { __half h; unsigned short u; } c; c.h = __float2half_rn(f); return c.u;
}
__device__ __forceinline__ __half2 u2h2(unsigned u) {
    union { unsigned u; __half2 h; } c; c.u = u; return c.h;
}
__device__ __forceinline__ unsigned h22u(__half2 h) {
    union { __half2 h; unsigned u; } c; c.h = h; return c.u;
}

// ---------------------------------------------------------------------------
// Weight prep (EXACT R12): wtf, wt2f (oc>=18 zero), wt1f. All fp16.
// ---------------------------------------------------------------------------
__global__ __launch_bounds__(256) void prep_weights(const float* __restrict__ dw,
                                                    const float* __restrict__ ow,
                                                    const float* __restrict__ cw,
                                                    unsigned short* __restrict__ wtf,
                                                    unsigned short* __restrict__ wt2f,
                                                    unsigned short* __restrict__ wt1f) {
    int idx = blockIdx.x * 256 + threadIdx.x;
    if (idx < WTF_N) {
        int j    = idx & 7;
        int lane = (idx >> 3) & 63;
        int nt   = (idx >> 9) & 3;
        int ks   = idx >> 11;
        int k    = ks * 32 + ((lane >> 4) << 3) + j;
        int tap  = k >> 6;
        int ic   = k & 63;
        int n    = nt * 16 + (lane & 15);
        wtf[idx] = f2h(dw[n * 576 + ic * 9 + tap]);
    }
    int i2 = idx - WTF_N;
    if (i2 >= 0 && i2 < WT2F_N) {
        int j    = i2 & 7;
        int lane = (i2 >> 3) & 63;
        int nt   = (i2 >> 9) & 1;
        int ks   = i2 >> 10;
        int k    = ks * 32 + ((lane >> 4) << 3) + j;
        int tap  = k >> 6;
        int ic   = k & 63;
        int n    = nt * 16 + (lane & 15);
        wt2f[i2] = (n < 18) ? f2h(ow[n * 576 + ic * 9 + tap]) : (unsigned short)0;
    }
    int i3 = idx - WTF_N - WT2F_N;
    if (i3 >= 0 && i3 < WT1F_N) {
        int j    = i3 & 7;
        int lane = (i3 >> 3) & 63;
        int nt   = (i3 >> 9) & 3;
        int n    = nt * 16 + (lane & 15);
        int k    = ((lane >> 4) << 3) + j;
        wt1f[i3] = (k < 27) ? f2h(cw[n * 27 + k]) : (unsigned short)0;
    }
}

// ---------------------------------------------------------------------------
// conv1 (EXACT R12): MFMA im2col GEMM, M=256 px, N=64 oc, K=32, fp16.
// ---------------------------------------------------------------------------
__global__ __launch_bounds__(256) void conv1_kernel(const float* __restrict__ x,
                                                    const unsigned short* __restrict__ wt1f,
                                                    const float* __restrict__ cb,
                                                    unsigned short* __restrict__ featp) {
    __shared__ unsigned short xs[10 * 264];   // rows 0..8 = (ic*3+ti), row 9 = zeros
    const int tid  = threadIdx.x;
    const int lane = tid & 63;
    const int wave = tid >> 6;
    const int lm   = lane & 15;
    const int quad = lane >> 4;

    const int bx = blockIdx.x;
    const int b  = bx >> 8;
    const int h  = bx & 255;

#pragma unroll
    for (int r = 0; r < 9; r++) {
        const int ic = r / 3, ti = r % 3;                 // static
        const int srow = h - 1 + ti;
        const bool rok = (unsigned)srow < 256u;
        const float* xrow = x + ((b * 3 + ic) << 16) + (srow << 8);
        {
            const int c = tid;
            float v = (rok && (unsigned)(c - 1) < 256u) ? xrow[c - 1] : 0.f;
            xs[r * 264 + c] = f2h(v);
        }
        if (tid < 2) {
            const int c = tid + 256;
            float v = (rok && (unsigned)(c - 1) < 256u) ? xrow[c - 1] : 0.f;
            xs[r * 264 + c] = f2h(v);
        }
    }
    xs[9 * 264 + tid] = 0;
    if (tid < 8) xs[9 * 264 + 256 + tid] = 0;
    __syncthreads();

    int off[8];
#pragma unroll
    for (int j = 0; j < 8; j++) {
        const int k = quad * 8 + j;
        const int row = (k < 27) ? (k / 3) : 9;
        const int tj  = (k < 27) ? (k - row * 3) : 0;
        off[j] = row * 264 + tj;
    }

    half8 bw[4];
#pragma unroll
    for (int nt = 0; nt < 4; nt++)
        bw[nt] = *(const half8*)(wt1f + nt * 512 + lane * 8);
    float bias[4];
#pragma unroll
    for (int nt = 0; nt < 4; nt++) bias[nt] = cb[nt * 16 + lm];

    unsigned short* fpx = featp + ((((size_t)b << 16) + (h << 8)) << 6);  // +px*64+oc

#pragma unroll
    for (int mt = 0; mt < 4; mt++) {
        const int px = wave * 64 + mt * 16 + lm;
        union { half8 v; unsigned u[4]; } af;
#pragma unroll
        for (int jj = 0; jj < 4; jj++) {
            unsigned lo = xs[off[2 * jj]     + px];
            unsigned hi = xs[off[2 * jj + 1] + px];
            af.u[jj] = lo | (hi << 16);
        }
        float4v d[4];
#pragma unroll
        for (int nt = 0; nt < 4; nt++)
            d[nt] = __builtin_amdgcn_mfma_f32_16x16x32_f16(af.v, bw[nt], (float4v)0.f, 0, 0, 0);

        const int pxs = wave * 64 + mt * 16 + quad * 4;
#pragma unroll
        for (int r = 0; r < 4; r++) {
            unsigned short* sp = fpx + (size_t)(pxs + r) * 64 + lm;
#pragma unroll
            for (int nt = 0; nt < 4; nt++)
                sp[nt * 16] = f2h(d[nt][r] + bias[nt]);
        }
    }
}

// ---------------------------------------------------------------------------
// FUSED conv2 + deform — R12 structure, WAVE-SPLIT: 512 threads = 8 waves,
// new wave wv = (old_wave*2 + mt): ow = wv>>1, mtb = wv&1. Every per-lane
// formula inherits the proven R12 (wave,mt) expressions verbatim; the mt
// loop is now a wave coordinate. LDS (ring 66KB + offl 9.5KB) unchanged ->
// still 2 blocks/CU but 16 waves/CU (2x occupancy), half per-wave state.
// ---------------------------------------------------------------------------
__global__ __launch_bounds__(512, 4) void fused_kernel(const unsigned short* __restrict__ featp,
                                                       const unsigned short* __restrict__ wt2f,
                                                       const float* __restrict__ ob,
                                                       const unsigned short* __restrict__ wtf,
                                                       const float* __restrict__ db,
                                                       float* __restrict__ out) {
    __shared__ __align__(16) unsigned char ring[4 * 132 * 128];   // 67584 B
    __shared__ float offl[4][18 * 33];                            // 9504 B

    const int tid  = threadIdx.x;
    const int lane = tid & 63;
    const int wv   = tid >> 6;          // 0..7
    const int ow   = wv >> 1;           // old wave 0..3
    const int mtb  = wv & 1;            // old mt 0..1
    const int lm   = lane & 15;
    const int quad = lane >> 4;

    const int bx = blockIdx.x;
    const int strip = ((bx & 7) << 8) | (bx >> 3);
    const int wo_base = (strip & 1) << 7;
    const int ho = (strip >> 1) & 255;
    const int b  = strip >> 9;

    const unsigned* fpq = (const unsigned*)featp + ((size_t)b << 21) + quad * 4;
    const int colb = wo_base + ow * 32 + mtb * 16 + lm;   // == old colb + mt*16
    float* offw = &offl[ow][0];

    const char* gbase = (const char*)featp + (((size_t)b << 16) << 7);  // batch byte base

// Stage feature row R (if valid) into ring slot R&3, swizzled (EXACT R12,
// stride 512 threads).
#define STAGE_ROW(R)                                                             \
    {                                                                            \
        const int rr = (R);                                                      \
        if ((unsigned)rr < 256u) {                                               \
            const char* gsrc = gbase + ((size_t)(rr << 8) << 7);                 \
            const unsigned base = (unsigned)((rr & 3) * 16896);                  \
            for (int c = tid; c < 1056; c += 512) {                              \
                const int xsl = c >> 3;                                          \
                const int col = wo_base - 2 + xsl;                               \
                if ((unsigned)col < 256u) {                                      \
                    uint4v v = *(const uint4v*)(gsrc + (((size_t)col) << 7)      \
                                                + ((c & 7) << 4));               \
                    const unsigned by = base + (unsigned)(c << 4);               \
                    *(uint4v*)(ring + (by ^ ((unsigned)((xsl & 7) << 4)))) = v;  \
                }                                                                \
            }                                                                    \
        }                                                                        \
    }

    STAGE_ROW(ho - 2);
    STAGE_ROW(ho - 1);
    STAGE_ROW(ho);
    STAGE_ROW(ho + 1);

    // ================= PHASE 1: offset conv (R12 body, single M-tile) =======
    {
        float4v acc1[2];
        acc1[0] = (float4v)0.f; acc1[1] = (float4v)0.f;

        uint4v A[2];

#define C2LOAD(KY, KX, DST)                                                      \
    {                                                                            \
        const int row = ho - 1 + (KY);                                           \
        const bool rok = (unsigned)row < 256u;                                   \
        const int col = colb + (KX) - 1;                                         \
        DST[0] = (uint4v)0;                                                      \
        DST[1] = (uint4v)0;                                                      \
        if (rok && (unsigned)col < 256u) {                                       \
            const unsigned* p = fpq + (((row << 8) + col) << 5);                 \
            DST[0] = *(const uint4v*)p;                                          \
            DST[1] = *(const uint4v*)(p + 16);                                   \
        }                                                                        \
    }

        C2LOAD(0, 0, A);

#pragma unroll
        for (int tap = 0; tap < 9; tap++) {
            half8 bfr[2][2];
            const unsigned short* wp = wt2f + (size_t)(tap * 2) * 1024 + lane * 8;
#pragma unroll
            for (int st = 0; st < 2; st++) {
                bfr[st][0] = *(const half8*)(wp + st * 1024);
                bfr[st][1] = *(const half8*)(wp + st * 1024 + 512);
            }
            uint4v N[2];
            if (tap < 8) {
                const int tn  = tap + 1;
                const int tky = tn / 3;
                const int tkx = tn - 3 * tky;
                C2LOAD(tky, tkx, N);
            }
            {
                union { half8 v; uint4v u; } f0, f1;
                f0.u = A[0]; f1.u = A[1];
                acc1[0] = __builtin_amdgcn_mfma_f32_16x16x32_f16(f0.v, bfr[0][0], acc1[0], 0, 0, 0);
                acc1[1] = __builtin_amdgcn_mfma_f32_16x16x32_f16(f0.v, bfr[0][1], acc1[1], 0, 0, 0);
                acc1[0] = __builtin_amdgcn_mfma_f32_16x16x32_f16(f1.v, bfr[1][0], acc1[0], 0, 0, 0);
                acc1[1] = __builtin_amdgcn_mfma_f32_16x16x32_f16(f1.v, bfr[1][1], acc1[1], 0, 0, 0);
            }
            if (tap < 8) { A[0] = N[0]; A[1] = N[1]; }
        }
#undef C2LOAD

        // Store offsets to per-(old-wave) LDS; this wave covers pxw slice
        // [mtb*16, mtb*16+16). (Reads happen after the barrier below.)
#pragma unroll
        for (int nt = 0; nt < 2; nt++) {
            int oc = nt * 16 + lm;
            if (oc < 18) {
                float bv = ob[oc];
#pragma unroll
                for (int r = 0; r < 4; r++)
                    offw[oc * 33 + mtb * 16 + quad * 4 + r] = acc1[nt][r] + bv;
            }
        }
    }

    __syncthreads();   // ring window (ho-2..ho+1) + all offsets published

    // ================= PHASE 2: deform conv (LDS-window gathers) ============
    const int wo0 = wo_base + ow * 32 + mtb * 16 + lm;   // == old wo0 + mt*16

    float4v acc[4];
#pragma unroll
    for (int nt = 0; nt < 4; nt++) acc[nt] = (float4v)0.f;

    union AFU { half8 v; unsigned u[4]; };

// One tap (EXACT R12 DOTAP_MT body, MT folded into wo0/mtb).
#define DOTAP(KY, KX, OY, OX)                                                    \
    {                                                                            \
        float sy = (float)(ho - 1 + (KY)) + (OY);                                \
        float sx = (float)(wo0 - 1 + (KX)) + (OX);                               \
        float y0f = floorf(sy), x0f = floorf(sx);                                \
        float dy = sy - y0f, dx = sx - x0f;                                      \
        int y0 = (int)y0f, x0 = (int)x0f;                                        \
        float wy0 = ((unsigned)y0 < 256u) ? (1.f - dy) : 0.f;                    \
        float wy1 = ((unsigned)(y0 + 1) < 256u) ? dy : 0.f;                      \
        float wx0 = ((unsigned)x0 < 256u) ? (1.f - dx) : 0.f;                    \
        float wx1 = ((unsigned)(x0 + 1) < 256u) ? dx : 0.f;                      \
        int yb0 = y0 < 0 ? 0 : (y0 > 255 ? 255 : y0);                            \
        int yb1 = (y0 + 1) < 0 ? 0 : ((y0 + 1) > 255 ? 255 : (y0 + 1));          \
        int xb0 = x0 < 0 ? 0 : (x0 > 255 ? 255 : x0);                            \
        int xb1 = (x0 + 1) < 0 ? 0 : ((x0 + 1) > 255 ? 255 : (x0 + 1));          \
        __half2 W0 = __float2half2_rn(wy0 * wx0);                                \
        __half2 W1 = __float2half2_rn(wy0 * wx1);                                \
        __half2 W2 = __float2half2_rn(wy1 * wx0);                                \
        __half2 W3 = __float2half2_rn(wy1 * wx1);                                \
        uint4v Gg[4][2];                                                         \
        bool inw = (yb0 >= ho - 2 + (KY)) && (yb1 <= ho + (KY) + 1) &&           \
                   (xb0 >= wo_base - 2) && (xb1 <= wo_base + 129);               \
        if (__all(inw)) {                                                        \
            const int xs0 = xb0 - wo_base + 2, xs1 = xb1 - wo_base + 2;          \
            const unsigned m0 = (unsigned)((xs0 & 7) << 4);                      \
            const unsigned m1 = (unsigned)((xs1 & 7) << 4);                      \
            const unsigned r0b = (unsigned)((yb0 & 3) * 16896 + quad * 16);      \
            const unsigned r1b = (unsigned)((yb1 & 3) * 16896 + quad * 16);      \
            const unsigned a00 = r0b + (unsigned)(xs0 << 7);                     \
            const unsigned a01 = r0b + (unsigned)(xs1 << 7);                     \
            const unsigned a10 = r1b + (unsigned)(xs0 << 7);                     \
            const unsigned a11 = r1b + (unsigned)(xs1 << 7);                     \
            Gg[0][0] = *(const uint4v*)(ring + (a00 ^ m0));                      \
            Gg[0][1] = *(const uint4v*)(ring + ((a00 + 64) ^ m0));               \
            Gg[1][0] = *(const uint4v*)(ring + (a01 ^ m1));                      \
            Gg[1][1] = *(const uint4v*)(ring + ((a01 + 64) ^ m1));               \
            Gg[2][0] = *(const uint4v*)(ring + (a10 ^ m0));                      \
            Gg[2][1] = *(const uint4v*)(ring + ((a10 + 64) ^ m0));               \
            Gg[3][0] = *(const uint4v*)(ring + (a11 ^ m1));                      \
            Gg[3][1] = *(const uint4v*)(ring + ((a11 + 64) ^ m1));               \
        } else {                                                                 \
            const unsigned e00 = ((yb0 << 8) + xb0) << 5;                        \
            const unsigned e01 = ((yb0 << 8) + xb1) << 5;                        \
            const unsigned e10 = ((yb1 << 8) + xb0) << 5;                        \
            const unsigned e11 = ((yb1 << 8) + xb1) << 5;                        \
            Gg[0][0] = *(const uint4v*)(fpq + e00);                              \
            Gg[0][1] = *(const uint4v*)(fpq + e00 + 16);                         \
            Gg[1][0] = *(const uint4v*)(fpq + e01);                              \
            Gg[1][1] = *(const uint4v*)(fpq + e01 + 16);                         \
            Gg[2][0] = *(const uint4v*)(fpq + e10);                              \
            Gg[2][1] = *(const uint4v*)(fpq + e10 + 16);                         \
            Gg[3][0] = *(const uint4v*)(fpq + e11);                              \
            Gg[3][1] = *(const uint4v*)(fpq + e11 + 16);                         \
        }                                                                        \
        AFU af[2];                                                               \
        _Pragma("unroll")                                                        \
        for (int st = 0; st < 2; st++) {                                         \
            _Pragma("unroll")                                                    \
            for (int j = 0; j < 4; j++) {                                        \
                __half2 s = __hmul2(W0, u2h2(Gg[0][st][j]));                     \
                s = __hfma2(W1, u2h2(Gg[1][st][j]), s);                          \
                s = __hfma2(W2, u2h2(Gg[2][st][j]), s);                          \
                s = __hfma2(W3, u2h2(Gg[3][st][j]), s);                          \
                af[st].u[j] = h22u(s);                                           \
            }                                                                    \
        }                                                                        \
        _Pragma("unroll")                                                        \
        for (int nt = 0; nt < 4; nt++)                                           \
            acc[nt] = __builtin_amdgcn_mfma_f32_16x16x32_f16(                    \
                af[0].v, bfr[0][nt], acc[nt], 0, 0, 0);                          \
        _Pragma("unroll")                                                        \
        for (int nt = 0; nt < 4; nt++)                                           \
            acc[nt] = __builtin_amdgcn_mfma_f32_16x16x32_f16(                    \
                af[1].v, bfr[1][nt], acc[nt], 0, 0, 0);                          \
    }

#pragma unroll
    for (int tap = 0; tap < 9; ++tap) {
        const int ky = tap / 3;
        const int kx = tap - 3 * ky;
        if (tap == 3) { __syncthreads(); STAGE_ROW(ho + 2); __syncthreads(); }
        if (tap == 6) { __syncthreads(); STAGE_ROW(ho + 3); __syncthreads(); }

        float oy = offw[(2 * tap) * 33 + mtb * 16 + lm];
        float ox = offw[(2 * tap + 1) * 33 + mtb * 16 + lm];

        half8 bfr[2][4];                                // B-frags, both steps
        {
            const unsigned short* wp = wtf + (size_t)tap * 4096 + lane * 8;
#pragma unroll
            for (int nt = 0; nt < 4; nt++) {
                bfr[0][nt] = *(const half8*)(wp + (nt << 9));
                bfr[1][nt] = *(const half8*)(wp + 2048 + (nt << 9));
            }
        }

        DOTAP(ky, kx, oy, ox);
    }

#pragma unroll
    for (int nt = 0; nt < 4; nt++) {
        int oc = nt * 16 + lm;
        float bv = db[oc];
        float* op = out + (((size_t)(b * 64 + oc)) << 16) + (ho << 8)
                  + wo_base + ow * 32 + mtb * 16 + quad * 4;
        float4 v = {acc[nt][0] + bv, acc[nt][1] + bv,
                    acc[nt][2] + bv, acc[nt][3] + bv};
        *(float4*)op = v;
    }
#undef DOTAP
#undef STAGE_ROW
}

// ---------------------------------------------------------------------------
extern "C" void kernel_launch(void* const* d_in, const int* in_sizes, int n_in,
                              void* d_out, int out_size, void* d_ws, size_t ws_size,
                              hipStream_t stream) {
    const float* x  = (const float*)d_in[0];
    const float* cw = (const float*)d_in[1];
    const float* cb = (const float*)d_in[2];
    const float* ow = (const float*)d_in[3];
    const float* ob = (const float*)d_in[4];
    const float* dw = (const float*)d_in[5];
    const float* db = (const float*)d_in[6];
    float* out = (float*)d_out;

    unsigned short* featp = (unsigned short*)d_ws;       // 33.5 MB fp16 NHWC
    float* offsb = (float*)(featp + FEAT_N);             // dead region — reuse
    unsigned short* wt1f = (unsigned short*)offsb;       // 4 KB conv1 B-frags
    unsigned short* wtf  = (unsigned short*)(offsb + OFFS_N);  // 72 KB
    unsigned short* wt2f = wtf + WTF_N;                  // 36 KB

    prep_weights<<<224, 256, 0, stream>>>(dw, ow, cw, wtf, wt2f, wt1f);
    conv1_kernel<<<1024, 256, 0, stream>>>(x, wt1f, cb, featp);
    fused_kernel<<<2048, 512, 0, stream>>>(featp, wt2f, ob, wtf, db, out);
}